// Round 4
// baseline (168.647 us; speedup 1.0000x reference)
//
#include <hip/hip_runtime.h>

#define BATCH 1024
#define PP 784          // 28*28

// ============= ONE fused kernel: conv + TDA + FC1 + FC2, one sample/block =============
// Conv is shuffle-free: lane x holds a 5-wide rolling input window (img cols
// x-2..x+2) and computes conv1 at x-1,x,x+1 in-lane, scattering conv2 taps into
// a static acc[28]. Window reads are hoisted across the 2 channel-pairs of each
// pass (2 passes x 2 cp). Edge zeroing folded into per-lane-masked w2 taps.
__global__ __launch_bounds__(256) void fused_kernel(
    const float* __restrict__ xin,
    const float* __restrict__ dtm1, const float* __restrict__ dtm2,
    const float* __restrict__ w1g, const float* __restrict__ b1g,
    const float* __restrict__ w2g, const float* __restrict__ b2g,
    const float* __restrict__ g1w, const float* __restrict__ g1b,
    const float* __restrict__ g2w, const float* __restrict__ g2b,
    const float* __restrict__ fc1w, const float* __restrict__ fc1b,
    const float* __restrict__ fc2w, const float* __restrict__ fc2b,
    float* __restrict__ out)
{
  const int b = blockIdx.x;
  const int tid = threadIdx.x;
  const int w = tid >> 6;          // wave id 0..3
  const int lane = tid & 63;
  const int x = lane & 31;         // x position (28 valid)
  const int sub = lane >> 5;       // sub-channel 0/1

  __shared__ float inL[28][36];    // col u+2 = img col u; cols 0,1,30..35 = 0
  __shared__ float w1L[9][32];     // [tap][c]
  __shared__ float w2L[9][32];
  __shared__ float b1L[32];
  __shared__ float pL[4][28][28];  // per-wave partial conv2 sums
  __shared__ __align__(16) float zL[864];   // 784 conv + 64 tda
  __shared__ float red[2][4][3];
  __shared__ float fin[2][3];
  __shared__ float pfc[4][64];
  __shared__ float z1L[64];

  // ---- phase 0: issue TDA loads early (latency hides under conv) ----
  float4 tv1, tv2;
  if (tid < 196) {
    tv1 = *(const float4*)&dtm1[b * PP + tid * 4];
    tv2 = *(const float4*)&dtm2[b * PP + tid * 4];
  }

  // ---- phase 1: stage input tile + weights ----
  for (int i = tid; i < 224; i += 256) {          // 8 pad cols x 28 rows
    int y = i >> 3, k = i & 7;
    inL[y][k < 2 ? k : k + 28] = 0.f;             // cols 0,1,30..35
  }
  for (int i = tid; i < 784; i += 256)
    inL[i / 28][i % 28 + 2] = xin[b * PP + i];
  for (int i = tid; i < 288; i += 256) {
    ((float*)w1L)[i] = w1g[i];
    ((float*)w2L)[i] = w2g[i];
  }
  if (tid < 32) b1L[tid] = b1g[tid];
  __syncthreads();

  // ---- phase 2: conv. wave w owns channels 8w..8w+7; pass g covers
  //      c = 8w+4g+{0,1,2,3} via (cp in {0,1}) x (sub) ----
  float acc[28];
#pragma unroll
  for (int y = 0; y < 28; ++y) acc[y] = 0.f;

#pragma unroll 1
  for (int g = 0; g < 2; ++g) {
    const int c0 = (w << 3) + (g << 2) + sub;
    const int c1 = c0 + 2;
    float wa0[9], wa1[9], wb0[9], wb1[9];
#pragma unroll
    for (int t = 0; t < 9; ++t) {
      wa0[t] = w1L[t][c0]; wa1[t] = w1L[t][c1];
      wb0[t] = w2L[t][c0]; wb1[t] = w2L[t][c1];
    }
    float bb0 = b1L[c0], bb1 = b1L[c1];
    if (x == 0)  { wb0[0]=wb0[3]=wb0[6]=0.f; wb1[0]=wb1[3]=wb1[6]=0.f; }
    if (x == 27) { wb0[2]=wb0[5]=wb0[8]=0.f; wb1[2]=wb1[5]=wb1[8]=0.f; }

    float A0=0.f,A1=0.f,A2=0.f,A3=0.f,A4=0.f;                    // row y-1
    float B0=inL[0][x],B1=inL[0][x+1],B2=inL[0][x+2],B3=inL[0][x+3],B4=inL[0][x+4];

#pragma unroll
    for (int y = 0; y < 28; ++y) {
      float C0,C1,C2,C3,C4;                                      // row y+1
      if (y < 27) {
        C0=inL[y+1][x]; C1=inL[y+1][x+1]; C2=inL[y+1][x+2];
        C3=inL[y+1][x+3]; C4=inL[y+1][x+4];
      } else { C0=0.f; C1=0.f; C2=0.f; C3=0.f; C4=0.f; }

#define CONV_CP(WA, WB, BB)                                                  \
      {                                                                      \
        float cm = BB, cc = BB, cp = BB;                                     \
        cm = fmaf(A0, WA[0], cm); cm = fmaf(A1, WA[1], cm); cm = fmaf(A2, WA[2], cm); \
        cm = fmaf(B0, WA[3], cm); cm = fmaf(B1, WA[4], cm); cm = fmaf(B2, WA[5], cm); \
        cm = fmaf(C0, WA[6], cm); cm = fmaf(C1, WA[7], cm); cm = fmaf(C2, WA[8], cm); \
        cc = fmaf(A1, WA[0], cc); cc = fmaf(A2, WA[1], cc); cc = fmaf(A3, WA[2], cc); \
        cc = fmaf(B1, WA[3], cc); cc = fmaf(B2, WA[4], cc); cc = fmaf(B3, WA[5], cc); \
        cc = fmaf(C1, WA[6], cc); cc = fmaf(C2, WA[7], cc); cc = fmaf(C3, WA[8], cc); \
        cp = fmaf(A2, WA[0], cp); cp = fmaf(A3, WA[1], cp); cp = fmaf(A4, WA[2], cp); \
        cp = fmaf(B2, WA[3], cp); cp = fmaf(B3, WA[4], cp); cp = fmaf(B4, WA[5], cp); \
        cp = fmaf(C2, WA[6], cp); cp = fmaf(C3, WA[7], cp); cp = fmaf(C4, WA[8], cp); \
        float hm = fmaxf(cm, 0.f), h0 = fmaxf(cc, 0.f), hp = fmaxf(cp, 0.f); \
        if (y < 27) {                                                        \
          acc[y+1] = fmaf(hm, WB[0], acc[y+1]);                              \
          acc[y+1] = fmaf(h0, WB[1], acc[y+1]);                              \
          acc[y+1] = fmaf(hp, WB[2], acc[y+1]);                              \
        }                                                                    \
        acc[y] = fmaf(hm, WB[3], acc[y]);                                    \
        acc[y] = fmaf(h0, WB[4], acc[y]);                                    \
        acc[y] = fmaf(hp, WB[5], acc[y]);                                    \
        if (y > 0) {                                                         \
          acc[y-1] = fmaf(hm, WB[6], acc[y-1]);                              \
          acc[y-1] = fmaf(h0, WB[7], acc[y-1]);                              \
          acc[y-1] = fmaf(hp, WB[8], acc[y-1]);                              \
        }                                                                    \
      }
      CONV_CP(wa0, wb0, bb0)
      CONV_CP(wa1, wb1, bb1)
#undef CONV_CP
      A0=B0; A1=B1; A2=B2; A3=B3; A4=B4;
      B0=C0; B1=C1; B2=C2; B3=C3; B4=C4;
    }
  }

  // reduce sub-channel halves; store per-wave partials
#pragma unroll
  for (int y = 0; y < 28; ++y) acc[y] += __shfl_xor(acc[y], 32);
  if (sub == 0 && x < 28) {
#pragma unroll
    for (int y = 0; y < 28; ++y) pL[w][y][x] = acc[y];
  }
  __syncthreads();

  // ---- phase 3a: conv epilogue -> zL[0..783]; TDA reduce ----
  {
    const float b2v = b2g[0];
    const float* pw = (const float*)pL;
    for (int u = tid; u < 784; u += 256) {
      float v = pw[u] + pw[784 + u] + pw[1568 + u] + pw[2352 + u] + b2v;
      zL[u] = fmaxf(v, 0.f);
    }
  }
#pragma unroll
  for (int br = 0; br < 2; ++br) {
    float m1 = 1e30f, m2 = 1e30f, mx = -1e30f;
    if (tid < 196) {
      float4 x4 = br ? tv2 : tv1;
      float xs[4] = {x4.x, x4.y, x4.z, x4.w};
#pragma unroll
      for (int k = 0; k < 4; ++k) {
        float v = xs[k];
        mx = fmaxf(mx, v);
        float nm1 = fminf(m1, v);
        m2 = fminf(m2, fmaxf(m1, v));
        m1 = nm1;
      }
    }
#pragma unroll
    for (int off = 32; off >= 1; off >>= 1) {
      float o1 = __shfl_xor(m1, off);
      float o2 = __shfl_xor(m2, off);
      float ox = __shfl_xor(mx, off);
      mx = fmaxf(mx, ox);
      float nm1 = fminf(m1, o1);
      m2 = fminf(fminf(m2, o2), fmaxf(m1, o1));
      m1 = nm1;
    }
    if ((tid & 63) == 0) {
      red[br][w][0] = m1; red[br][w][1] = m2; red[br][w][2] = mx;
    }
  }
  __syncthreads();
  if (tid < 2) {
    float m1 = 1e30f, m2 = 1e30f, mx = -1e30f;
#pragma unroll
    for (int wv = 0; wv < 4; ++wv) {
      float o1 = red[tid][wv][0], o2 = red[tid][wv][1], ox = red[tid][wv][2];
      mx = fmaxf(mx, ox);
      float nm1 = fminf(m1, o1);
      m2 = fminf(fminf(m2, o2), fmaxf(m1, o1));
      m1 = nm1;
    }
    fin[tid][0] = m1; fin[tid][1] = m2; fin[tid][2] = mx;
  }
  __syncthreads();
  // ---- phase 3b: landscape @ g_w -> zL[784..847] ----
  if (tid < 64) {
    const int br = tid >> 5, j = tid & 31;
    const float m1 = fin[br][0], m2 = fin[br][1], mx = fin[br][2];
    const float* gw = br ? g2w : g1w;
    const float* gb = br ? g2b : g1b;
    const float t0 = br ? 0.05f : 0.01f;
    const float dt = br ? (0.25f / 31.0f) : (0.28f / 31.0f);
    float a = gb[j];
#pragma unroll 4
    for (int i = 0; i < 64; ++i) {
      const int k = i >> 5, ti = i & 31;
      float tv = t0 + dt * (float)ti;
      float vk = k ? m2 : m1;
      float lam = fmaxf(0.0f, fminf(tv - vk, mx - tv));
      a = fmaf(lam, gw[i * 32 + j], a);
    }
    zL[784 + br * 32 + j] = fmaxf(a, 0.0f);
  }
  __syncthreads();

  // ---- phase 4: FC1 (j = tid&63, 4-way split over i) ----
  {
    const int j = tid & 63, part = tid >> 6;
    float a = 0.f;
    const int i0 = part * 212;
#pragma unroll 4
    for (int i = i0; i < i0 + 212; i += 4) {
      float4 z4 = *(float4*)&zL[i];
      a = fmaf(z4.x, fc1w[(i + 0) * 64 + j], a);
      a = fmaf(z4.y, fc1w[(i + 1) * 64 + j], a);
      a = fmaf(z4.z, fc1w[(i + 2) * 64 + j], a);
      a = fmaf(z4.w, fc1w[(i + 3) * 64 + j], a);
    }
    pfc[part][j] = a;
  }
  __syncthreads();
  if (tid < 64) {
    float v = pfc[0][tid] + pfc[1][tid] + pfc[2][tid] + pfc[3][tid] + fc1b[tid];
    z1L[tid] = fmaxf(v, 0.f);
  }
  __syncthreads();
  // ---- FC2 ----
  if (tid < 10) {
    float a = fc2b[tid];
#pragma unroll 8
    for (int jj = 0; jj < 64; ++jj)
      a = fmaf(z1L[jj], fc2w[jj * 10 + tid], a);
    out[b * 10 + tid] = a;
  }
}

extern "C" void kernel_launch(void* const* d_in, const int* in_sizes, int n_in,
                              void* d_out, int out_size, void* d_ws, size_t ws_size,
                              hipStream_t stream) {
  const float* x       = (const float*)d_in[0];
  const float* dtm005  = (const float*)d_in[1];
  const float* dtm02   = (const float*)d_in[2];
  const float* conv_w1 = (const float*)d_in[3];
  const float* conv_b1 = (const float*)d_in[4];
  const float* conv_w2 = (const float*)d_in[5];
  const float* conv_b2 = (const float*)d_in[6];
  const float* g1_w    = (const float*)d_in[7];
  const float* g1_b    = (const float*)d_in[8];
  const float* g2_w    = (const float*)d_in[9];
  const float* g2_b    = (const float*)d_in[10];
  const float* fc1_w   = (const float*)d_in[11];
  const float* fc1_b   = (const float*)d_in[12];
  const float* fc2_w   = (const float*)d_in[13];
  const float* fc2_b   = (const float*)d_in[14];
  float* out = (float*)d_out;

  fused_kernel<<<BATCH, 256, 0, stream>>>(
      x, dtm005, dtm02, conv_w1, conv_b1, conv_w2, conv_b2,
      g1_w, g1_b, g2_w, g2_b, fc1_w, fc1_b, fc2_w, fc2_b, out);
}

// Round 5
// 112.742 us; speedup vs baseline: 1.4959x; 1.4959x over previous
//
#include <hip/hip_runtime.h>

#define BATCH 1024
#define PP 784          // 28*28

// DPP wave-wide lane shifts (VALU pipe — no LDS traffic).
// wave_shr1 (0x138): lane l gets lane l-1; lane 0 -> 0 (bound_ctrl:0).
// wave_shl1 (0x130): lane l gets lane l+1; lane 63 -> 0.
__device__ __forceinline__ float dpp_wave_shr1(float v) {
  return __int_as_float(__builtin_amdgcn_update_dpp(
      0, __float_as_int(v), 0x138, 0xF, 0xF, true));
}
__device__ __forceinline__ float dpp_wave_shl1(float v) {
  return __int_as_float(__builtin_amdgcn_update_dpp(
      0, __float_as_int(v), 0x130, 0xF, 0xF, true));
}

// ============= ONE fused kernel: conv + TDA + FC1 + FC2, one sample/block =============
// Conv: single pass over input rows (y-loop NOT unrolled — tiny body), 4
// channel-pairs inner sharing the 3-wide window; h x-neighbors via DPP wave
// shifts; conv2 accumulated in a 3-register rolling window (aM/aC/aP), one
// pL row written per y. 8 pL slots (per wave x sub) so no cross-lane reduce.
__global__ __launch_bounds__(256, 4) void fused_kernel(
    const float* __restrict__ xin,
    const float* __restrict__ dtm1, const float* __restrict__ dtm2,
    const float* __restrict__ w1g, const float* __restrict__ b1g,
    const float* __restrict__ w2g, const float* __restrict__ b2g,
    const float* __restrict__ g1w, const float* __restrict__ g1b,
    const float* __restrict__ g2w, const float* __restrict__ g2b,
    const float* __restrict__ fc1w, const float* __restrict__ fc1b,
    const float* __restrict__ fc2w, const float* __restrict__ fc2b,
    float* __restrict__ out)
{
  const int b = blockIdx.x;
  const int tid = threadIdx.x;
  const int w = tid >> 6;          // wave id 0..3
  const int lane = tid & 63;
  const int x = lane & 31;         // x position (28 valid)

  __shared__ float inL[28][36];    // col0=0, col u+1 = img col u, cols 29..35 = 0
  __shared__ __align__(16) float wTL[2][32][12];  // [arr][c][tap0..8,pad]
  __shared__ float b1L[32];
  __shared__ __align__(16) float pL[8][28][28];   // per (wave,sub) conv2 partials
  __shared__ __align__(16) float zL[864];          // 784 conv + 64 tda
  __shared__ float red[2][4][3];

  // ---- phase 0: TDA loads early (latency hides under conv) ----
  float4 tv1, tv2;
  if (tid < 196) {
    tv1 = *(const float4*)&dtm1[b * PP + tid * 4];
    tv2 = *(const float4*)&dtm2[b * PP + tid * 4];
  }

  // ---- phase 1: stage input tile + transposed weights ----
  for (int i = tid; i < 224; i += 256) {          // 8 pad cols x 28 rows
    int y = i >> 3, k = i & 7;
    inL[y][k == 0 ? 0 : 28 + k] = 0.f;            // cols 0, 29..35
  }
  for (int i = tid; i < 784; i += 256)
    inL[i / 28][i % 28 + 1] = xin[b * PP + i];
  for (int i = tid; i < 288; i += 256) {          // [tap][c] -> [c][tap]
    int c = i & 31, t = i >> 5;
    wTL[0][c][t] = w1g[i];
    wTL[1][c][t] = w2g[i];
  }
  if (tid < 32) b1L[tid] = b1g[tid];
  __syncthreads();

  // ---- phase 2: conv. wave w, sub = lane>>5; channels c = 8w+2cp+sub ----
  {
    const int sub = lane >> 5;
    const int slot = tid >> 5;                    // 0..7 = 2w+sub
    float4 waA[4], waB[4], wbA[4], wbB[4];
    float wa8[4], wb8[4], bb[4];
#pragma unroll
    for (int cp = 0; cp < 4; ++cp) {
      const int c = (w << 3) + (cp << 1) + sub;
      const float* p1 = &wTL[0][c][0];
      const float* p2 = &wTL[1][c][0];
      waA[cp] = *(const float4*)p1; waB[cp] = *(const float4*)(p1 + 4); wa8[cp] = p1[8];
      wbA[cp] = *(const float4*)p2; wbB[cp] = *(const float4*)(p2 + 4); wb8[cp] = p2[8];
      bb[cp] = b1L[c];
    }

    float A0 = 0.f, A1 = 0.f, A2 = 0.f;                       // input row y-1
    float B0 = inL[0][x], B1 = inL[0][x + 1], B2 = inL[0][x + 2];  // row y
    float aM = 0.f, aC = 0.f, aP = 0.f;  // conv2 partials for out rows y-1,y,y+1

#pragma unroll 2
    for (int y = 0; y < 28; ++y) {
      float C0, C1, C2;                                       // input row y+1
      if (y < 27) {
        C0 = inL[y + 1][x]; C1 = inL[y + 1][x + 1]; C2 = inL[y + 1][x + 2];
      } else { C0 = 0.f; C1 = 0.f; C2 = 0.f; }

#pragma unroll
      for (int cp = 0; cp < 4; ++cp) {
        float h = bb[cp];
        h = fmaf(A0, waA[cp].x, h); h = fmaf(A1, waA[cp].y, h); h = fmaf(A2, waA[cp].z, h);
        h = fmaf(B0, waA[cp].w, h); h = fmaf(B1, waB[cp].x, h); h = fmaf(B2, waB[cp].y, h);
        h = fmaf(C0, waB[cp].z, h); h = fmaf(C1, waB[cp].w, h); h = fmaf(C2, wa8[cp], h);
        h = (x < 28) ? fmaxf(h, 0.f) : 0.f;   // zero pad lanes -> free edge handling
        float hl = dpp_wave_shr1(h);          // h at x-1 (0 at x==0 via lane31-zero/bound)
        float hr = dpp_wave_shl1(h);          // h at x+1 (0 at x==27 via lane28-zero)
        aP = fmaf(hl, wbA[cp].x, aP); aP = fmaf(h, wbA[cp].y, aP); aP = fmaf(hr, wbA[cp].z, aP);
        aC = fmaf(hl, wbA[cp].w, aC); aC = fmaf(h, wbB[cp].x, aC); aC = fmaf(hr, wbB[cp].y, aC);
        aM = fmaf(hl, wbB[cp].z, aM); aM = fmaf(h, wbB[cp].w, aM); aM = fmaf(hr, wb8[cp], aM);
      }
      if (y > 0 && x < 28) pL[slot][y - 1][x] = aM;   // out row y-1 complete
      aM = aC; aC = aP; aP = 0.f;
      A0 = B0; A1 = B1; A2 = B2;
      B0 = C0; B1 = C1; B2 = C2;
    }
    if (x < 28) pL[slot][27][x] = aM;                 // out row 27
  }
  __syncthreads();

  // ---- phase 3a: conv epilogue -> zL[0..783]; TDA per-wave reduce ----
  {
    const float b2v = b2g[0];
    const float* pw = (const float*)pL;
    for (int u = tid; u < 784; u += 256) {
      float v = pw[u] + pw[784 + u] + pw[1568 + u] + pw[2352 + u]
              + pw[3136 + u] + pw[3920 + u] + pw[4704 + u] + pw[5488 + u] + b2v;
      zL[u] = fmaxf(v, 0.f);
    }
  }
#pragma unroll
  for (int br = 0; br < 2; ++br) {
    float m1 = 1e30f, m2 = 1e30f, mx = -1e30f;
    if (tid < 196) {
      float4 x4 = br ? tv2 : tv1;
      float xs[4] = {x4.x, x4.y, x4.z, x4.w};
#pragma unroll
      for (int k = 0; k < 4; ++k) {
        float v = xs[k];
        mx = fmaxf(mx, v);
        float nm1 = fminf(m1, v);
        m2 = fminf(m2, fmaxf(m1, v));
        m1 = nm1;
      }
    }
#pragma unroll
    for (int off = 32; off >= 1; off >>= 1) {
      float o1 = __shfl_xor(m1, off);
      float o2 = __shfl_xor(m2, off);
      float ox = __shfl_xor(mx, off);
      mx = fmaxf(mx, ox);
      float nm1 = fminf(m1, o1);
      m2 = fminf(fminf(m2, o2), fmaxf(m1, o1));
      m1 = nm1;
    }
    if ((tid & 63) == 0) {
      red[br][w][0] = m1; red[br][w][1] = m2; red[br][w][2] = mx;
    }
  }
  __syncthreads();

  // ---- phase 3b: wave 0 finishes TDA (cross-wave reduce in-lane + landscape) ----
  if (tid < 64) {
    const int br = tid >> 5, j = tid & 31;
    float m1 = 1e30f, m2 = 1e30f, mx = -1e30f;
#pragma unroll
    for (int wv = 0; wv < 4; ++wv) {
      float o1 = red[br][wv][0], o2 = red[br][wv][1], ox = red[br][wv][2];
      mx = fmaxf(mx, ox);
      float nm1 = fminf(m1, o1);
      m2 = fminf(fminf(m2, o2), fmaxf(m1, o1));
      m1 = nm1;
    }
    const float* gw = br ? g2w : g1w;
    const float* gb = br ? g2b : g1b;
    const float t0 = br ? 0.05f : 0.01f;
    const float dt = br ? (0.25f / 31.0f) : (0.28f / 31.0f);
    float a = gb[j];
#pragma unroll 4
    for (int i = 0; i < 64; ++i) {
      const int k = i >> 5, ti = i & 31;
      float tv = t0 + dt * (float)ti;
      float vk = k ? m2 : m1;
      float lam = fmaxf(0.0f, fminf(tv - vk, mx - tv));
      a = fmaf(lam, gw[i * 32 + j], a);
    }
    zL[784 + br * 32 + j] = fmaxf(a, 0.0f);
  }
  __syncthreads();

  // ---- phase 4: FC1. thread = (part = tid>>4 over i, jq = tid&15 over j4) ----
  float* pfcF = &pL[0][0][0];          // pL is dead; alias for fc partials
  {
    const int part = tid >> 4, jq = tid & 15;
    float ax = 0.f, ay = 0.f, az = 0.f, aw = 0.f;
    const int i0 = part * 53;          // 848 = 16*53
    for (int i = i0; i < i0 + 53; ++i) {
      float zv = zL[i];
      float4 w4 = *(const float4*)&fc1w[i * 64 + jq * 4];
      ax = fmaf(zv, w4.x, ax); ay = fmaf(zv, w4.y, ay);
      az = fmaf(zv, w4.z, az); aw = fmaf(zv, w4.w, aw);
    }
    *(float4*)&pfcF[part * 64 + jq * 4] = make_float4(ax, ay, az, aw);
  }
  __syncthreads();
  // ---- phase 5: wave 0 reduces 16 parts, relu, FC2 ----
  {
    float* z1L = pfcF + 1024;
    if (tid < 64) {
      float v = fc1b[tid];
#pragma unroll
      for (int p = 0; p < 16; ++p) v += pfcF[p * 64 + tid];
      z1L[tid] = fmaxf(v, 0.f);
    }
    if (tid < 10) {
      float a = fc2b[tid];
#pragma unroll 8
      for (int jj = 0; jj < 64; ++jj)
        a = fmaf(z1L[jj], fc2w[jj * 10 + tid], a);
      out[b * 10 + tid] = a;
    }
  }
}

extern "C" void kernel_launch(void* const* d_in, const int* in_sizes, int n_in,
                              void* d_out, int out_size, void* d_ws, size_t ws_size,
                              hipStream_t stream) {
  const float* x       = (const float*)d_in[0];
  const float* dtm005  = (const float*)d_in[1];
  const float* dtm02   = (const float*)d_in[2];
  const float* conv_w1 = (const float*)d_in[3];
  const float* conv_b1 = (const float*)d_in[4];
  const float* conv_w2 = (const float*)d_in[5];
  const float* conv_b2 = (const float*)d_in[6];
  const float* g1_w    = (const float*)d_in[7];
  const float* g1_b    = (const float*)d_in[8];
  const float* g2_w    = (const float*)d_in[9];
  const float* g2_b    = (const float*)d_in[10];
  const float* fc1_w   = (const float*)d_in[11];
  const float* fc1_b   = (const float*)d_in[12];
  const float* fc2_w   = (const float*)d_in[13];
  const float* fc2_b   = (const float*)d_in[14];
  float* out = (float*)d_out;

  fused_kernel<<<BATCH, 256, 0, stream>>>(
      x, dtm005, dtm02, conv_w1, conv_b1, conv_w2, conv_b2,
      g1_w, g1_b, g2_w, g2_b, fc1_w, fc1_b, fc2_w, fc2_b, out);
}